// Round 19
// baseline (121.485 us; speedup 1.0000x reference)
//
#include <hip/hip_runtime.h>
#include <math.h>

#define CIN   32
#define COUT  32
#define HH    256
#define WW    256
#define BB    16
#define SDIM  512

#define XT    16
#define YT    16
#define NXT   16
#define NTILE 256           // 16x16 tiles per (b,co)

typedef __attribute__((ext_vector_type(8))) short bf16x8;
typedef __attribute__((ext_vector_type(4))) float f32x4;
typedef __attribute__((ext_vector_type(8))) unsigned short u16x8;

__device__ __forceinline__ unsigned bf16_rne_bits(float x) {
    unsigned u = __float_as_uint(x);
    return (u + 0x7fffu + ((u >> 16) & 1u)) >> 16;   // round-nearest-even bf16
}

// ---------------- fused prep+repack ----------------
// grid 4672: bid<4096 -> repack (NCHW fp32 -> slot-permuted NHWC bf16, LDS-bounce);
//            bid>=4096 -> weight prep (s in LDS, then wmod hi/lo pack).
// Paths independent; block 4096 also zeroes the 64B OOB buffer for conv reads.
__global__ __launch_bounds__(256) void fused_prep_kernel(
    const float* __restrict__ input,
    const float* __restrict__ style,
    const float* __restrict__ mod_weight,
    const float* __restrict__ mod_bias,
    const float* __restrict__ weight,
    unsigned short* __restrict__ nhwc,
    unsigned short* __restrict__ Wk,
    float* __restrict__ zbuf) {
    __shared__ __align__(16) unsigned short lt[256 * 40];   // 20 KB (union)
    const int bid = blockIdx.x;
    const int tid = threadIdx.x;

    if (bid < 4096) {
        // ---- repack path ----
        const int gy = bid & 255;
        const int b  = bid >> 8;

        #pragma unroll
        for (int it = 0; it < 2; ++it) {
            int idx = it * 256 + tid;
            int xf  = idx & 63;             // x = 4*xf..+3
            int cg  = idx >> 6;             // ci = 4*cg..+3
            const float* ip = input + (((b * 32 + cg * 4) * 256 + gy) * 256) + xf * 4;
            float4 v0 = *(const float4*)(ip);
            float4 v1 = *(const float4*)(ip + 65536);
            float4 v2 = *(const float4*)(ip + 131072);
            float4 v3 = *(const float4*)(ip + 196608);
            float a0[4] = {v0.x, v0.y, v0.z, v0.w};
            float a1[4] = {v1.x, v1.y, v1.z, v1.w};
            float a2[4] = {v2.x, v2.y, v2.z, v2.w};
            float a3[4] = {v3.x, v3.y, v3.z, v3.w};
            #pragma unroll
            for (int m = 0; m < 4; ++m) {
                uint2 p;
                p.x = bf16_rne_bits(a0[m]) | (bf16_rne_bits(a1[m]) << 16);
                p.y = bf16_rne_bits(a2[m]) | (bf16_rne_bits(a3[m]) << 16);
                *(uint2*)&lt[(xf * 4 + m) * 40 + cg * 4] = p;
            }
        }
        __syncthreads();

        unsigned short* cb = nhwc + (((((b << 8) + gy) << 8)) << 5);
        #pragma unroll
        for (int it = 0; it < 4; ++it) {
            int idx  = it * 256 + tid;
            int slot = idx & 3;
            int gx   = idx >> 2;
            int o    = (slot - ((gx + 1) >> 1)) & 3;
            bf16x8 v = *(const bf16x8*)&lt[gx * 40 + o * 8];
            *(bf16x8*)(cb + (gx << 5) + slot * 8) = v;
        }
    } else {
        // ---- weight prep path: 576 blocks, 36 per batch ----
        const int wblk = bid - 4096;            // 0..575
        const int b    = wblk / 36;             // single b per block
        if (wblk == 0 && tid < 16) zbuf[tid] = 0.f;

        float* s_lds = (float*)lt;
        if (tid < 32) {
            const int ci = tid;
            const float mscale = 0.044194173824159216f;  // 1/sqrt(512)
            const float* st = style + b * SDIM;
            const float* mw = mod_weight + ci * SDIM;
            float acc = 0.f;
            for (int d = 0; d < SDIM; d += 4) {
                acc += st[d]   * mw[d]
                     + st[d+1] * mw[d+1]
                     + st[d+2] * mw[d+2]
                     + st[d+3] * mw[d+3];
            }
            s_lds[ci] = acc * mscale + mod_bias[ci];
        }
        __syncthreads();

        const int idx = wblk * 256 + tid;       // < 147456 always
        const float wscale = 0.05892556509887896f;   // 1/sqrt(32*3*3)
        int r  = idx % (COUT * CIN * 9);
        int co = r / (CIN * 9);
        int r2 = r % (CIN * 9);
        int ci = r2 / 9;
        int w  = r2 % 9;
        float wm = wscale * weight[co * (CIN * 9) + ci * 9 + w] * s_lds[ci];
        unsigned hb = bf16_rne_bits(wm);
        float hif = __uint_as_float(hb << 16);
        unsigned lb = bf16_rne_bits(wm - hif);
        int base = ((b * 9 + w) * 2) * 1024 + co * 32 + ci;
        Wk[base]        = (unsigned short)hb;   // part 0: hi (consumed)
        Wk[base + 1024] = (unsigned short)lb;   // part 1: lo (fallback only)
    }
}

// ---------------- MFMA conv: DIRECT global fragment reads (no x LDS) -----------
// grid 4096 (XCD-swizzled), 4 waves, LDS = 1KB stats only -> VGPR-bound occupancy.
// A wave's xv reads are contiguous 1KB spans of nhwc (lane t,g -> chunk gx=x0-1+
// t+kw, slot (g+(u>>1))&3; slot algebra matches repack since 8*xt == 0 mod 4).
// Block footprint 20.7KB < 32KB L1 -> kw passes 2,3 mostly L1-hit.
// OOB halo lanes read the 64B zero buffer (per-load select).
// NOTE: (256,6)+LDS-staging was 48us; (512,8)/(256,7) spill; kw full-unroll
// +28us (r15); 2-tile dbuf +5us (r16). No min-waves arg here (cap lesson).
__global__ __launch_bounds__(256) void conv_mfma_kernel(
    const unsigned short* __restrict__ nhwc,
    const unsigned short* __restrict__ Wk,
    const unsigned short* __restrict__ zbuf16,
    unsigned short* __restrict__ bfout,
    float2* __restrict__ partials) {

    __shared__ float2 stats[4 * 32];

    const int tid = threadIdx.x;
    // bijective XCD swizzle: each XCD gets 512 consecutive sw ids (2 b-slices)
    const int wg = blockIdx.x;
    const int sw = (wg & 7) * 512 + (wg >> 3);
    const int b  = sw >> 8;
    const int yt = (sw >> 4) & 15;
    const int xt = sw & 15;

    const int x0 = xt * XT, y0 = yt * YT;
    const int t  = tid & 15;
    const int g  = (tid >> 4) & 3;
    const int wv = tid >> 6;
    const int f  = wv & 1;
    const int rbase = 8 * (wv >> 1);

    f32x4 acc[8];
    #pragma unroll
    for (int i = 0; i < 8; ++i) acc[i] = (f32x4){0.f, 0.f, 0.f, 0.f};

    #pragma unroll 1
    for (int kw = 0; kw < 3; ++kw) {
        const int u  = t + kw;                  // 0..17
        const int gx = x0 - 1 + u;              // -1..256 at edges
        const bool col_ok = (unsigned)gx < 256u;
        const int slot = (g + (u >> 1)) & 3;

        bf16x8 wf[3];
        const unsigned short* wb =
            Wk + (b * 9 * 2) * 1024 + f * 512 + t * 32 + g * 8;
        #pragma unroll
        for (int kh = 0; kh < 3; ++kh)
            wf[kh] = *(const bf16x8*)(wb + ((kh * 3 + kw) * 2) * 1024);

        // 10 direct global fragment loads (coalesced 1KB/wave, L1-resident)
        bf16x8 xv[10];
        const unsigned short* colbase =
            nhwc + ((((b << 8) << 8) + gx) << 5) + slot * 8;
        const unsigned short* zp = zbuf16 + slot * 8;
        #pragma unroll
        for (int y = 0; y < 10; ++y) {
            const int gy = y0 - 1 + rbase + y;
            const bool ok = col_ok && ((unsigned)gy < 256u);
            const unsigned short* p = ok ? colbase + ((long)gy << 13) : zp;
            xv[y] = *(const bf16x8*)p;
        }

        #pragma unroll
        for (int kh = 0; kh < 3; ++kh)
            #pragma unroll
            for (int i = 0; i < 8; ++i)
                acc[i] = __builtin_amdgcn_mfma_f32_16x16x32_bf16(
                    wf[kh], xv[i + kh], acc[i], 0, 0, 0);
    }

    // ---- epilogue: bf16 stores + stats ----
    float s_[4] = {0.f, 0.f, 0.f, 0.f}, q_[4] = {0.f, 0.f, 0.f, 0.f};
    #pragma unroll
    for (int i = 0; i < 8; ++i) {
        const int gy = y0 + rbase + i;
        #pragma unroll
        for (int r = 0; r < 4; ++r) {
            float v = acc[i][r];
            const int off = (b * 32 + 16 * f + 4 * g + r) * 65536 + gy * 256 + x0 + t;
            bfout[off] = (unsigned short)bf16_rne_bits(v);
            s_[r] += v;
            q_[r] += v * v;
        }
    }
    #pragma unroll
    for (int r = 0; r < 4; ++r) {
        #pragma unroll
        for (int off = 1; off < 16; off <<= 1) {
            s_[r] += __shfl_xor(s_[r], off);
            q_[r] += __shfl_xor(q_[r], off);
        }
    }
    if (t == 0) {
        #pragma unroll
        for (int r = 0; r < 4; ++r)
            stats[wv * 32 + 16 * f + 4 * g + r] = make_float2(s_[r], q_[r]);
    }
    __syncthreads();
    if (tid < 32) {
        int w0 = (tid < 16) ? 0 : 1;            // waves 0/2 own co<16, 1/3 co>=16
        float2 a = stats[w0 * 32 + tid];
        float2 c = stats[(w0 + 2) * 32 + tid];
        partials[(b * 32 + tid) * NTILE + yt * NXT + xt] =
            make_float2(a.x + c.x, a.y + c.y);
    }
}

// ---------------- fused reduce+scale: 4 blocks per (b,co) channel --------------
__global__ __launch_bounds__(256) void reduce_scale_kernel(
    const float2* __restrict__ partials,
    const unsigned short* __restrict__ bf,
    float* __restrict__ out) {
    __shared__ float wsum[4], wsq[4];
    __shared__ float inv_s;
    const int bid = blockIdx.x;
    const int c   = bid >> 2;          // channel 0..511
    const int q   = bid & 3;           // quarter
    const int tid = threadIdx.x;

    float2 p = partials[c * 256 + tid];
    float s = p.x, sq = p.y;
    #pragma unroll
    for (int off = 1; off < 64; off <<= 1) {
        s  += __shfl_xor(s,  off);
        sq += __shfl_xor(sq, off);
    }
    if ((tid & 63) == 0) { wsum[tid >> 6] = s; wsq[tid >> 6] = sq; }
    __syncthreads();
    if (tid == 0) {
        float S = wsum[0] + wsum[1] + wsum[2] + wsum[3];
        float Q = wsq[0]  + wsq[1]  + wsq[2]  + wsq[3];
        const float N = 65536.f;
        float var = (Q - S * S / N) / (N - 1.f);   // unbiased (ddof=1)
        inv_s = 1.0f / sqrtf(var);
    }
    __syncthreads();
    const float m = inv_s;

    const unsigned short* src = bf  + c * 65536 + q * 16384;
    float*                dst = out + c * 65536 + q * 16384;
    #pragma unroll
    for (int it = 0; it < 8; ++it) {
        int i = (it * 256 + tid) * 8;
        u16x8 v = *(const u16x8*)&src[i];
        float4 a, cc;
        a.x  = __uint_as_float(((unsigned)v[0]) << 16) * m;
        a.y  = __uint_as_float(((unsigned)v[1]) << 16) * m;
        a.z  = __uint_as_float(((unsigned)v[2]) << 16) * m;
        a.w  = __uint_as_float(((unsigned)v[3]) << 16) * m;
        cc.x = __uint_as_float(((unsigned)v[4]) << 16) * m;
        cc.y = __uint_as_float(((unsigned)v[5]) << 16) * m;
        cc.z = __uint_as_float(((unsigned)v[6]) << 16) * m;
        cc.w = __uint_as_float(((unsigned)v[7]) << 16) * m;
        *(float4*)&dst[i]     = a;
        *(float4*)&dst[i + 4] = cc;
    }
}

extern "C" void kernel_launch(void* const* d_in, const int* in_sizes, int n_in,
                              void* d_out, int out_size, void* d_ws, size_t ws_size,
                              hipStream_t stream) {
    const float* input      = (const float*)d_in[0];
    const float* style      = (const float*)d_in[1];
    const float* weight     = (const float*)d_in[2];
    const float* mod_weight = (const float*)d_in[3];
    const float* mod_bias   = (const float*)d_in[4];
    float* out = (float*)d_out;
    char*  ws  = (char*)d_ws;

    unsigned short* Wk       = (unsigned short*)(ws + 2048);      // 589824 B
    float2*         partials = (float2*)(ws + 2048 + 589824);     // 1048576 B
    float*          zbuf     = (float*)(ws + 2048 + 589824 + 1048576 + 2048); // 64 B
    const size_t    bf_off   = 2048 + 589824 + 1048576 + 2048 + 64;
    unsigned short* bfout    = (unsigned short*)(ws + bf_off);    // 67108864 B

    // NHWC bf16 intermediate lives in d_out's first 67MB; conv consumes it
    // before reduce_scale overwrites all of d_out. Deterministic across replays.
    unsigned short* nhwc = (unsigned short*)d_out;

    fused_prep_kernel<<<4672, 256, 0, stream>>>(
        input, style, mod_weight, mod_bias, weight, nhwc, Wk, zbuf);
    conv_mfma_kernel<<<4096, 256, 0, stream>>>(
        nhwc, Wk, (const unsigned short*)zbuf, bfout, partials);
    reduce_scale_kernel<<<2048, 256, 0, stream>>>(partials, bfout, out);
}

// Round 20
// 117.611 us; speedup vs baseline: 1.0329x; 1.0329x over previous
//
#include <hip/hip_runtime.h>
#include <math.h>

#define CIN   32
#define COUT  32
#define HH    256
#define WW    256
#define BB    16
#define SDIM  512

#define XT    16
#define NXT   16
#define NTILE 256           // 16 ytp x 16 xt per (b,co)

typedef __attribute__((ext_vector_type(8))) short bf16x8;
typedef __attribute__((ext_vector_type(4))) float f32x4;
typedef __attribute__((ext_vector_type(8))) unsigned short u16x8;

__device__ __forceinline__ unsigned bf16_rne_bits(float x) {
    unsigned u = __float_as_uint(x);
    return (u + 0x7fffu + ((u >> 16) & 1u)) >> 16;   // round-nearest-even bf16
}

// ---------------- fused prep+repack ----------------
// grid 4672: bid<4096 -> repack (NCHW fp32 -> slot-permuted NHWC bf16, LDS-bounce);
//            bid>=4096 -> weight prep (s in LDS, then wmod hi/lo pack).
// Paths independent; block 4096 also zeroes the 64B OOB buffer for conv staging.
__global__ __launch_bounds__(256) void fused_prep_kernel(
    const float* __restrict__ input,
    const float* __restrict__ style,
    const float* __restrict__ mod_weight,
    const float* __restrict__ mod_bias,
    const float* __restrict__ weight,
    unsigned short* __restrict__ nhwc,
    unsigned short* __restrict__ Wk,
    float* __restrict__ zbuf) {
    __shared__ __align__(16) unsigned short lt[256 * 40];   // 20 KB (union)
    const int bid = blockIdx.x;
    const int tid = threadIdx.x;

    if (bid < 4096) {
        // ---- repack path ----
        const int gy = bid & 255;
        const int b  = bid >> 8;

        #pragma unroll
        for (int it = 0; it < 2; ++it) {
            int idx = it * 256 + tid;
            int xf  = idx & 63;             // x = 4*xf..+3
            int cg  = idx >> 6;             // ci = 4*cg..+3
            const float* ip = input + (((b * 32 + cg * 4) * 256 + gy) * 256) + xf * 4;
            float4 v0 = *(const float4*)(ip);
            float4 v1 = *(const float4*)(ip + 65536);
            float4 v2 = *(const float4*)(ip + 131072);
            float4 v3 = *(const float4*)(ip + 196608);
            float a0[4] = {v0.x, v0.y, v0.z, v0.w};
            float a1[4] = {v1.x, v1.y, v1.z, v1.w};
            float a2[4] = {v2.x, v2.y, v2.z, v2.w};
            float a3[4] = {v3.x, v3.y, v3.z, v3.w};
            #pragma unroll
            for (int m = 0; m < 4; ++m) {
                uint2 p;
                p.x = bf16_rne_bits(a0[m]) | (bf16_rne_bits(a1[m]) << 16);
                p.y = bf16_rne_bits(a2[m]) | (bf16_rne_bits(a3[m]) << 16);
                *(uint2*)&lt[(xf * 4 + m) * 40 + cg * 4] = p;
            }
        }
        __syncthreads();

        unsigned short* cb = nhwc + (((((b << 8) + gy) << 8)) << 5);
        #pragma unroll
        for (int it = 0; it < 4; ++it) {
            int idx  = it * 256 + tid;
            int slot = idx & 3;
            int gx   = idx >> 2;
            int o    = (slot - ((gx + 1) >> 1)) & 3;
            bf16x8 v = *(const bf16x8*)&lt[gx * 40 + o * 8];
            *(bf16x8*)(cb + (gx << 5) + slot * 8) = v;
        }
    } else {
        // ---- weight prep path: 576 blocks, 36 per batch ----
        const int wblk = bid - 4096;            // 0..575
        const int b    = wblk / 36;             // single b per block
        if (wblk == 0 && tid < 16) zbuf[tid] = 0.f;

        float* s_lds = (float*)lt;
        if (tid < 32) {
            const int ci = tid;
            const float mscale = 0.044194173824159216f;  // 1/sqrt(512)
            const float* st = style + b * SDIM;
            const float* mw = mod_weight + ci * SDIM;
            float acc = 0.f;
            for (int d = 0; d < SDIM; d += 4) {
                acc += st[d]   * mw[d]
                     + st[d+1] * mw[d+1]
                     + st[d+2] * mw[d+2]
                     + st[d+3] * mw[d+3];
            }
            s_lds[ci] = acc * mscale + mod_bias[ci];
        }
        __syncthreads();

        const int idx = wblk * 256 + tid;       // < 147456 always
        const float wscale = 0.05892556509887896f;   // 1/sqrt(32*3*3)
        int r  = idx % (COUT * CIN * 9);
        int co = r / (CIN * 9);
        int r2 = r % (CIN * 9);
        int ci = r2 / 9;
        int w  = r2 % 9;
        float wm = wscale * weight[co * (CIN * 9) + ci * 9 + w] * s_lds[ci];
        unsigned hb = bf16_rne_bits(wm);
        float hif = __uint_as_float(hb << 16);
        unsigned lb = bf16_rne_bits(wm - hif);
        int base = ((b * 9 + w) * 2) * 1024 + co * 32 + ci;
        Wk[base]        = (unsigned short)hb;   // part 0: hi (consumed)
        Wk[base + 1024] = (unsigned short)lb;   // part 1: lo (fallback only)
    }
}

// ---------------- MFMA conv: 2-wave blocks, two sequential 8-row sub-tiles ------
// grid 4096 (XCD-swizzled), 128 threads, ~12KB LDS -> 13 blocks/CU (26 waves):
// 2.2x more independent barrier-domains than r18's 6x4-wave config, so one
// block's DMA drain overlaps another's MFMA. Staging per sub-tile: 720 x 16B
// global->LDS DMA (linear LDS dest, swizzle pre-baked in nhwc); OOB lanes read
// the 64B zero buffer. Stats accumulate in regs across sub-tiles (NTILE=256
// unchanged). Error: x-bf16 + single-term weights, measured absmax 0.03125.
// NOTE: (512,8)/(256,7) launch-bounds spill; kw full-unroll +28us (r15);
// same-block dbuf +5us (r16); direct-global (no LDS) +8us (r19). No min-waves.
__global__ __launch_bounds__(128) void conv_mfma_kernel(
    const unsigned short* __restrict__ nhwc,
    const unsigned short* __restrict__ Wk,
    const float* __restrict__ zbuf,
    unsigned short* __restrict__ bfout,
    float2* __restrict__ partials) {

    __shared__ __align__(16) unsigned short xlds[10 * 576];   // 11.25 KB
    __shared__ float2 stats[32];

    const int tid = threadIdx.x;
    // bijective XCD swizzle: each XCD gets 512 consecutive sw ids (2 b-slices)
    const int wg  = blockIdx.x;
    const int sw  = (wg & 7) * 512 + (wg >> 3);
    const int b   = sw >> 8;
    const int ytp = (sw >> 4) & 15;
    const int xt  = sw & 15;

    const int x0 = xt * XT;
    const int t  = tid & 15;
    const int g  = (tid >> 4) & 3;
    const int f  = tid >> 6;          // wave = co half

    float s_[4] = {0.f, 0.f, 0.f, 0.f}, q_[4] = {0.f, 0.f, 0.f, 0.f};

    #pragma unroll 1
    for (int sub = 0; sub < 2; ++sub) {
        const int y0 = ytp * 16 + sub * 8;

        // ---- staging: 720 x 16B global->LDS DMA (10 rows x 18 u x 4 slots) ----
        #pragma unroll
        for (int it = 0; it < 6; ++it) {
            int idx = it * 128 + tid;
            if (idx < 720) {
                int s  = idx & 3;
                int cu = idx >> 2;          // y*18 + u
                int u  = cu % 18;
                int y  = cu / 18;
                int gy = y0 - 1 + y, gx = x0 - 1 + u;
                bool ok = ((unsigned)gy < 256u) && ((unsigned)gx < 256u);
                const unsigned short* src = ok
                    ? nhwc + (((((b << 8) + gy) << 8) + gx) << 5) + s * 8
                    : (const unsigned short*)zbuf + s * 8;
                __builtin_amdgcn_global_load_lds(
                    (const __attribute__((address_space(1))) unsigned int*)src,
                    (__attribute__((address_space(3))) unsigned int*)
                        ((char*)xlds + (idx << 4)),
                    16, 0, 0);
            }
        }
        __syncthreads();

        // ---- compute: 3 kw-passes, each {3 weight frags, 10 row frags, 24 MFMA}
        f32x4 acc[8];
        #pragma unroll
        for (int i = 0; i < 8; ++i) acc[i] = (f32x4){0.f, 0.f, 0.f, 0.f};

        #pragma unroll 1
        for (int kw = 0; kw < 3; ++kw) {
            const int u = t + kw;                    // 0..17, always staged
            const int slot = (g + (u >> 1)) & 3;

            bf16x8 wf[3];
            const unsigned short* wb =
                Wk + (b * 9 * 2) * 1024 + f * 512 + t * 32 + g * 8;
            #pragma unroll
            for (int kh = 0; kh < 3; ++kh)
                wf[kh] = *(const bf16x8*)(wb + ((kh * 3 + kw) * 2) * 1024);

            bf16x8 xv[10];
            #pragma unroll
            for (int y = 0; y < 10; ++y)
                xv[y] = *(const bf16x8*)&xlds[y * 576 + u * 32 + slot * 8];

            #pragma unroll
            for (int kh = 0; kh < 3; ++kh)
                #pragma unroll
                for (int i = 0; i < 8; ++i)
                    acc[i] = __builtin_amdgcn_mfma_f32_16x16x32_bf16(
                        wf[kh], xv[i + kh], acc[i], 0, 0, 0);
        }

        // ---- stores + stats accumulation (no partial write yet) ----
        #pragma unroll
        for (int i = 0; i < 8; ++i) {
            const int gy = y0 + i;
            #pragma unroll
            for (int r = 0; r < 4; ++r) {
                float v = acc[i][r];
                const int off =
                    (b * 32 + 16 * f + 4 * g + r) * 65536 + gy * 256 + x0 + t;
                bfout[off] = (unsigned short)bf16_rne_bits(v);
                s_[r] += v;
                q_[r] += v * v;
            }
        }
        __syncthreads();   // all xlds reads done before sub-tile 1 overwrites
    }

    // ---- epilogue: t-reduce, one partial per channel for the 16x16 tile ----
    #pragma unroll
    for (int r = 0; r < 4; ++r) {
        #pragma unroll
        for (int off = 1; off < 16; off <<= 1) {
            s_[r] += __shfl_xor(s_[r], off);
            q_[r] += __shfl_xor(q_[r], off);
        }
    }
    if (t == 0) {
        #pragma unroll
        for (int r = 0; r < 4; ++r)
            stats[16 * f + 4 * g + r] = make_float2(s_[r], q_[r]);
    }
    __syncthreads();
    if (tid < 32)
        partials[(b * 32 + tid) * NTILE + ytp * NXT + xt] = stats[tid];
}

// ---------------- fused reduce+scale: 4 blocks per (b,co) channel --------------
__global__ __launch_bounds__(256) void reduce_scale_kernel(
    const float2* __restrict__ partials,
    const unsigned short* __restrict__ bf,
    float* __restrict__ out) {
    __shared__ float wsum[4], wsq[4];
    __shared__ float inv_s;
    const int bid = blockIdx.x;
    const int c   = bid >> 2;          // channel 0..511
    const int q   = bid & 3;           // quarter
    const int tid = threadIdx.x;

    float2 p = partials[c * 256 + tid];
    float s = p.x, sq = p.y;
    #pragma unroll
    for (int off = 1; off < 64; off <<= 1) {
        s  += __shfl_xor(s,  off);
        sq += __shfl_xor(sq, off);
    }
    if ((tid & 63) == 0) { wsum[tid >> 6] = s; wsq[tid >> 6] = sq; }
    __syncthreads();
    if (tid == 0) {
        float S = wsum[0] + wsum[1] + wsum[2] + wsum[3];
        float Q = wsq[0]  + wsq[1]  + wsq[2]  + wsq[3];
        const float N = 65536.f;
        float var = (Q - S * S / N) / (N - 1.f);   // unbiased (ddof=1)
        inv_s = 1.0f / sqrtf(var);
    }
    __syncthreads();
    const float m = inv_s;

    const unsigned short* src = bf  + c * 65536 + q * 16384;
    float*                dst = out + c * 65536 + q * 16384;
    #pragma unroll
    for (int it = 0; it < 8; ++it) {
        int i = (it * 256 + tid) * 8;
        u16x8 v = *(const u16x8*)&src[i];
        float4 a, cc;
        a.x  = __uint_as_float(((unsigned)v[0]) << 16) * m;
        a.y  = __uint_as_float(((unsigned)v[1]) << 16) * m;
        a.z  = __uint_as_float(((unsigned)v[2]) << 16) * m;
        a.w  = __uint_as_float(((unsigned)v[3]) << 16) * m;
        cc.x = __uint_as_float(((unsigned)v[4]) << 16) * m;
        cc.y = __uint_as_float(((unsigned)v[5]) << 16) * m;
        cc.z = __uint_as_float(((unsigned)v[6]) << 16) * m;
        cc.w = __uint_as_float(((unsigned)v[7]) << 16) * m;
        *(float4*)&dst[i]     = a;
        *(float4*)&dst[i + 4] = cc;
    }
}

extern "C" void kernel_launch(void* const* d_in, const int* in_sizes, int n_in,
                              void* d_out, int out_size, void* d_ws, size_t ws_size,
                              hipStream_t stream) {
    const float* input      = (const float*)d_in[0];
    const float* style      = (const float*)d_in[1];
    const float* weight     = (const float*)d_in[2];
    const float* mod_weight = (const float*)d_in[3];
    const float* mod_bias   = (const float*)d_in[4];
    float* out = (float*)d_out;
    char*  ws  = (char*)d_ws;

    unsigned short* Wk       = (unsigned short*)(ws + 2048);      // 589824 B
    float2*         partials = (float2*)(ws + 2048 + 589824);     // 1048576 B
    float*          zbuf     = (float*)(ws + 2048 + 589824 + 1048576 + 2048); // 64 B
    const size_t    bf_off   = 2048 + 589824 + 1048576 + 2048 + 64;
    unsigned short* bfout    = (unsigned short*)(ws + bf_off);    // 67108864 B

    // NHWC bf16 intermediate lives in d_out's first 67MB; conv consumes it
    // before reduce_scale overwrites all of d_out. Deterministic across replays.
    unsigned short* nhwc = (unsigned short*)d_out;

    fused_prep_kernel<<<4672, 256, 0, stream>>>(
        input, style, mod_weight, mod_bias, weight, nhwc, Wk, zbuf);
    conv_mfma_kernel<<<4096, 128, 0, stream>>>(nhwc, Wk, zbuf, bfout, partials);
    reduce_scale_kernel<<<2048, 256, 0, stream>>>(partials, bfout, out);
}

// Round 21
// 114.148 us; speedup vs baseline: 1.0643x; 1.0303x over previous
//
#include <hip/hip_runtime.h>
#include <math.h>

#define CIN   32
#define COUT  32
#define HH    256
#define WW    256
#define BB    16
#define SDIM  512

#define XT    16
#define YT    16
#define NXT   16
#define NTILE 256           // 16x16 tiles per (b,co)

typedef __attribute__((ext_vector_type(8))) short bf16x8;
typedef __attribute__((ext_vector_type(4))) float f32x4;
typedef __attribute__((ext_vector_type(8))) unsigned short u16x8;

__device__ __forceinline__ unsigned bf16_rne_bits(float x) {
    unsigned u = __float_as_uint(x);
    return (u + 0x7fffu + ((u >> 16) & 1u)) >> 16;   // round-nearest-even bf16
}

// ---------------- fused prep+repack ----------------
// grid 4672: bid<4096 -> repack (NCHW fp32 -> slot-permuted NHWC bf16, LDS-bounce);
//            bid>=4096 -> weight prep (s in LDS, then wmod hi/lo pack).
// Paths independent; block 4096 also zeroes the 64B OOB buffer for conv staging.
__global__ __launch_bounds__(256) void fused_prep_kernel(
    const float* __restrict__ input,
    const float* __restrict__ style,
    const float* __restrict__ mod_weight,
    const float* __restrict__ mod_bias,
    const float* __restrict__ weight,
    unsigned short* __restrict__ nhwc,
    unsigned short* __restrict__ Wk,
    float* __restrict__ zbuf) {
    __shared__ __align__(16) unsigned short lt[256 * 40];   // 20 KB (union)
    const int bid = blockIdx.x;
    const int tid = threadIdx.x;

    if (bid < 4096) {
        // ---- repack path ----
        const int gy = bid & 255;
        const int b  = bid >> 8;

        #pragma unroll
        for (int it = 0; it < 2; ++it) {
            int idx = it * 256 + tid;
            int xf  = idx & 63;             // x = 4*xf..+3
            int cg  = idx >> 6;             // ci = 4*cg..+3
            const float* ip = input + (((b * 32 + cg * 4) * 256 + gy) * 256) + xf * 4;
            float4 v0 = *(const float4*)(ip);
            float4 v1 = *(const float4*)(ip + 65536);
            float4 v2 = *(const float4*)(ip + 131072);
            float4 v3 = *(const float4*)(ip + 196608);
            float a0[4] = {v0.x, v0.y, v0.z, v0.w};
            float a1[4] = {v1.x, v1.y, v1.z, v1.w};
            float a2[4] = {v2.x, v2.y, v2.z, v2.w};
            float a3[4] = {v3.x, v3.y, v3.z, v3.w};
            #pragma unroll
            for (int m = 0; m < 4; ++m) {
                uint2 p;
                p.x = bf16_rne_bits(a0[m]) | (bf16_rne_bits(a1[m]) << 16);
                p.y = bf16_rne_bits(a2[m]) | (bf16_rne_bits(a3[m]) << 16);
                *(uint2*)&lt[(xf * 4 + m) * 40 + cg * 4] = p;
            }
        }
        __syncthreads();

        unsigned short* cb = nhwc + (((((b << 8) + gy) << 8)) << 5);
        #pragma unroll
        for (int it = 0; it < 4; ++it) {
            int idx  = it * 256 + tid;
            int slot = idx & 3;
            int gx   = idx >> 2;
            int o    = (slot - ((gx + 1) >> 1)) & 3;
            bf16x8 v = *(const bf16x8*)&lt[gx * 40 + o * 8];
            *(bf16x8*)(cb + (gx << 5) + slot * 8) = v;
        }
    } else {
        // ---- weight prep path: 576 blocks, 36 per batch ----
        const int wblk = bid - 4096;            // 0..575
        const int b    = wblk / 36;             // single b per block
        if (wblk == 0 && tid < 16) zbuf[tid] = 0.f;

        float* s_lds = (float*)lt;
        if (tid < 32) {
            const int ci = tid;
            const float mscale = 0.044194173824159216f;  // 1/sqrt(512)
            const float* st = style + b * SDIM;
            const float* mw = mod_weight + ci * SDIM;
            float acc = 0.f;
            for (int d = 0; d < SDIM; d += 4) {
                acc += st[d]   * mw[d]
                     + st[d+1] * mw[d+1]
                     + st[d+2] * mw[d+2]
                     + st[d+3] * mw[d+3];
            }
            s_lds[ci] = acc * mscale + mod_bias[ci];
        }
        __syncthreads();

        const int idx = wblk * 256 + tid;       // < 147456 always
        const float wscale = 0.05892556509887896f;   // 1/sqrt(32*3*3)
        int r  = idx % (COUT * CIN * 9);
        int co = r / (CIN * 9);
        int r2 = r % (CIN * 9);
        int ci = r2 / 9;
        int w  = r2 % 9;
        float wm = wscale * weight[co * (CIN * 9) + ci * 9 + w] * s_lds[ci];
        unsigned hb = bf16_rne_bits(wm);
        float hif = __uint_as_float(hb << 16);
        unsigned lb = bf16_rne_bits(wm - hif);
        int base = ((b * 9 + w) * 2) * 1024 + co * 32 + ci;
        Wk[base]        = (unsigned short)hb;   // part 0: hi (consumed)
        Wk[base + 1024] = (unsigned short)lb;   // part 1: lo (fallback only)
    }
}

// ---------------- MFMA conv: global_load_lds staging, stats overlay in xlds ----
// grid 4096 (XCD-swizzled), 4 waves, LDS = 20736B -> 7 blocks/CU (28 waves).
// Staging: 1296 x 16B direct global->LDS DMA; LDS dest linear (base+lane*16),
// swizzle pre-baked in nhwc; OOB lanes read a 64B zero buffer.
// Stats buffer overlays xlds after a post-compute barrier (r11 pattern) to
// keep the block under the 21KB LDS granule that allowed only 6 blocks in r18.
// NOTE: (256,6)-era experiments: (512,8)/(256,7) spill; kw full-unroll +28us
// (r15); same-block dbuf +5us (r16); no-LDS direct reads +8us (r19); 2-wave
// sub-tiles +4us (r20). This staged 4-wave shape is the measured optimum.
__global__ __launch_bounds__(256) void conv_mfma_kernel(
    const unsigned short* __restrict__ nhwc,
    const unsigned short* __restrict__ Wk,
    const float* __restrict__ zbuf,
    unsigned short* __restrict__ bfout,
    float2* __restrict__ partials) {

    __shared__ __align__(16) unsigned short xlds[18 * 576];   // 20736 B total

    const int tid = threadIdx.x;
    // bijective XCD swizzle: each XCD gets 512 consecutive sw ids (2 b-slices)
    const int wg = blockIdx.x;
    const int sw = (wg & 7) * 512 + (wg >> 3);
    const int b  = sw >> 8;
    const int yt = (sw >> 4) & 15;
    const int xt = sw & 15;

    const int x0 = xt * XT, y0 = yt * YT;
    const int t  = tid & 15;
    const int g  = (tid >> 4) & 3;
    const int wv = tid >> 6;
    const int f  = wv & 1;
    const int rbase = 8 * (wv >> 1);

    // ---- staging: 1296 x 16B global->LDS DMA (6 per thread) ----
    #pragma unroll
    for (int it = 0; it < 6; ++it) {
        int idx = it * 256 + tid;
        if (idx < 1296) {
            int s  = idx & 3;
            int cu = idx >> 2;          // y*18 + u
            int u  = cu % 18;
            int y  = cu / 18;
            int gy = y0 - 1 + y, gx = x0 - 1 + u;
            bool ok = ((unsigned)gy < 256u) && ((unsigned)gx < 256u);
            const unsigned short* src = ok
                ? nhwc + (((((b << 8) + gy) << 8) + gx) << 5) + s * 8
                : (const unsigned short*)zbuf + s * 8;
            __builtin_amdgcn_global_load_lds(
                (const __attribute__((address_space(1))) unsigned int*)src,
                (__attribute__((address_space(3))) unsigned int*)
                    ((char*)xlds + (idx << 4)),
                16, 0, 0);
        }
    }
    __syncthreads();

    // ---- compute: 3 kw-passes, each {3 weight frags, 10 row frags, 24 MFMA} ----
    f32x4 acc[8];
    #pragma unroll
    for (int i = 0; i < 8; ++i) acc[i] = (f32x4){0.f, 0.f, 0.f, 0.f};

    #pragma unroll 1
    for (int kw = 0; kw < 3; ++kw) {
        const int u = t + kw;                    // 0..17, always staged
        const int slot = (g + (u >> 1)) & 3;

        bf16x8 wf[3];
        const unsigned short* wb =
            Wk + (b * 9 * 2) * 1024 + f * 512 + t * 32 + g * 8;
        #pragma unroll
        for (int kh = 0; kh < 3; ++kh)
            wf[kh] = *(const bf16x8*)(wb + ((kh * 3 + kw) * 2) * 1024);

        bf16x8 xv[10];
        #pragma unroll
        for (int y = 0; y < 10; ++y)
            xv[y] = *(const bf16x8*)&xlds[(rbase + y) * 576 + u * 32 + slot * 8];

        #pragma unroll
        for (int kh = 0; kh < 3; ++kh)
            #pragma unroll
            for (int i = 0; i < 8; ++i)
                acc[i] = __builtin_amdgcn_mfma_f32_16x16x32_bf16(
                    wf[kh], xv[i + kh], acc[i], 0, 0, 0);
    }

    // ---- epilogue: bf16 stores + stats (stats overlays xlds after barrier) ----
    float s_[4] = {0.f, 0.f, 0.f, 0.f}, q_[4] = {0.f, 0.f, 0.f, 0.f};
    #pragma unroll
    for (int i = 0; i < 8; ++i) {
        const int gy = y0 + rbase + i;
        #pragma unroll
        for (int r = 0; r < 4; ++r) {
            float v = acc[i][r];
            const int off = (b * 32 + 16 * f + 4 * g + r) * 65536 + gy * 256 + x0 + t;
            bfout[off] = (unsigned short)bf16_rne_bits(v);
            s_[r] += v;
            q_[r] += v * v;
        }
    }
    #pragma unroll
    for (int r = 0; r < 4; ++r) {
        #pragma unroll
        for (int off = 1; off < 16; off <<= 1) {
            s_[r] += __shfl_xor(s_[r], off);
            q_[r] += __shfl_xor(q_[r], off);
        }
    }
    __syncthreads();                       // all xlds fragment reads complete
    float2* stats = (float2*)xlds;         // 1KB overlay
    if (t == 0) {
        #pragma unroll
        for (int r = 0; r < 4; ++r)
            stats[wv * 32 + 16 * f + 4 * g + r] = make_float2(s_[r], q_[r]);
    }
    __syncthreads();
    if (tid < 32) {
        int w0 = (tid < 16) ? 0 : 1;            // waves 0/2 own co<16, 1/3 co>=16
        float2 a = stats[w0 * 32 + tid];
        float2 c = stats[(w0 + 2) * 32 + tid];
        partials[(b * 32 + tid) * NTILE + yt * NXT + xt] =
            make_float2(a.x + c.x, a.y + c.y);
    }
}

// ---------------- fused reduce+scale: 4 blocks per (b,co) channel --------------
__global__ __launch_bounds__(256) void reduce_scale_kernel(
    const float2* __restrict__ partials,
    const unsigned short* __restrict__ bf,
    float* __restrict__ out) {
    __shared__ float wsum[4], wsq[4];
    __shared__ float inv_s;
    const int bid = blockIdx.x;
    const int c   = bid >> 2;          // channel 0..511
    const int q   = bid & 3;           // quarter
    const int tid = threadIdx.x;

    float2 p = partials[c * 256 + tid];
    float s = p.x, sq = p.y;
    #pragma unroll
    for (int off = 1; off < 64; off <<= 1) {
        s  += __shfl_xor(s,  off);
        sq += __shfl_xor(sq, off);
    }
    if ((tid & 63) == 0) { wsum[tid >> 6] = s; wsq[tid >> 6] = sq; }
    __syncthreads();
    if (tid == 0) {
        float S = wsum[0] + wsum[1] + wsum[2] + wsum[3];
        float Q = wsq[0]  + wsq[1]  + wsq[2]  + wsq[3];
        const float N = 65536.f;
        float var = (Q - S * S / N) / (N - 1.f);   // unbiased (ddof=1)
        inv_s = 1.0f / sqrtf(var);
    }
    __syncthreads();
    const float m = inv_s;

    const unsigned short* src = bf  + c * 65536 + q * 16384;
    float*                dst = out + c * 65536 + q * 16384;
    #pragma unroll
    for (int it = 0; it < 8; ++it) {
        int i = (it * 256 + tid) * 8;
        u16x8 v = *(const u16x8*)&src[i];
        float4 a, cc;
        a.x  = __uint_as_float(((unsigned)v[0]) << 16) * m;
        a.y  = __uint_as_float(((unsigned)v[1]) << 16) * m;
        a.z  = __uint_as_float(((unsigned)v[2]) << 16) * m;
        a.w  = __uint_as_float(((unsigned)v[3]) << 16) * m;
        cc.x = __uint_as_float(((unsigned)v[4]) << 16) * m;
        cc.y = __uint_as_float(((unsigned)v[5]) << 16) * m;
        cc.z = __uint_as_float(((unsigned)v[6]) << 16) * m;
        cc.w = __uint_as_float(((unsigned)v[7]) << 16) * m;
        *(float4*)&dst[i]     = a;
        *(float4*)&dst[i + 4] = cc;
    }
}

extern "C" void kernel_launch(void* const* d_in, const int* in_sizes, int n_in,
                              void* d_out, int out_size, void* d_ws, size_t ws_size,
                              hipStream_t stream) {
    const float* input      = (const float*)d_in[0];
    const float* style      = (const float*)d_in[1];
    const float* weight     = (const float*)d_in[2];
    const float* mod_weight = (const float*)d_in[3];
    const float* mod_bias   = (const float*)d_in[4];
    float* out = (float*)d_out;
    char*  ws  = (char*)d_ws;

    unsigned short* Wk       = (unsigned short*)(ws + 2048);      // 589824 B
    float2*         partials = (float2*)(ws + 2048 + 589824);     // 1048576 B
    float*          zbuf     = (float*)(ws + 2048 + 589824 + 1048576 + 2048); // 64 B
    const size_t    bf_off   = 2048 + 589824 + 1048576 + 2048 + 64;
    unsigned short* bfout    = (unsigned short*)(ws + bf_off);    // 67108864 B

    // NHWC bf16 intermediate lives in d_out's first 67MB; conv consumes it
    // before reduce_scale overwrites all of d_out. Deterministic across replays.
    unsigned short* nhwc = (unsigned short*)d_out;

    fused_prep_kernel<<<4672, 256, 0, stream>>>(
        input, style, mod_weight, mod_bias, weight, nhwc, Wk, zbuf);
    conv_mfma_kernel<<<4096, 256, 0, stream>>>(nhwc, Wk, zbuf, bfout, partials);
    reduce_scale_kernel<<<2048, 256, 0, stream>>>(partials, bfout, out);
}